// Round 15
// baseline (217.874 us; speedup 1.0000x reference)
//
#include <hip/hip_runtime.h>
#include <hip/hip_bf16.h>

// LSS voxel pooling: replicated per-segment buckets + counting-sort gather.
//   x:    (B=8, N=6, D=41, H=16, W=44, C=64) f32
//   geom: (B, N, D, H, W, 3) f32
//   out:  (B, C=64, X=200, Y=200) f32
//
// bin = (b*200 + ix)*200 + iy,  kept iff 0<=ix<200, 0<=iy<200, iz==0
// (IEEE fp32 add + div + trunc-toward-zero matches reference .astype(int32))
//
// Pipeline (3 dispatches):
//   0 memset     : zero 8x3200 replica counters + ovf counter (100 KB)
//   1 rep_scatter: seg = bin/100, rep = blockIdx&7 (~XCD-local -> no cross-XCD
//                  counter bouncing; 8x replication cuts RMW chains 341->43).
//                  slot = atomicAdd(segcnt[rep][seg]); write packed
//                  (pid<<8|iy%100) into segbuf[seg][rep][slot]. 13 MB buffer
//                  is L2-resident -> writeback coalescing. Overflow -> global
//                  list folded by gather (correctness never depends on caps).
//   2 gather12   : block = segment (100 bins = half (b,ix) row). Stage the 8
//                  contiguous sub-lists into LDS (8 reps x 32 lanes), LDS
//                  counting sort by iy (hist + 128-scan + cursor scatter),
//                  equal 16-way point split across quarter-waves, double-
//                  buffered float4 x loads (2x6 dwordx4 in flight), register
//                  run accumulation, run flush = 4 LDS atomicAdd (~450/blk),
//                  fold overflow, coalesced out-write. 35.3 KB -> 4 blk/CU.

#define NP        1385472
#define NP_PER_B  173184      // N*D*H*W
#define NXY       200
#define NBIN      320000      // 8*200*200
#define NSEG      3200        // NBIN/100
#define NREP      8
#define CAPR      128         // per-replica segment capacity (mean 43)
#define CAPRSH    7
#define OVF_CAP   4096
#define UNR       6           // x-loads per batch; 2 batches in flight
#define TSTRIDE   65          // tile row stride (odd -> conflict-free)
#define LSIZE     1024        // = NREP*CAPR, sort buffer cap (mean 341)

// ---------------- phase 1: replicated segment-bucket scatter ----------------
__global__ void rep_scatter(const float* __restrict__ geom,
                            int* __restrict__ segcnt,        // [NREP][NSEG]
                            unsigned int* __restrict__ segbuf, // [NSEG][NREP][CAPR]
                            int* __restrict__ ovf_cnt,
                            int* __restrict__ ovf) {
    int p = blockIdx.x * 256 + threadIdx.x;
    if (p >= NP) return;
    float gx = geom[(size_t)p * 3 + 0];
    float gy = geom[(size_t)p * 3 + 1];
    float gz = geom[(size_t)p * 3 + 2];
    int ix = (int)((gx + 50.0f) / 0.5f);
    int iy = (int)((gy + 50.0f) / 0.5f);
    int iz = (int)((gz + 10.0f) / 20.0f);
    if (ix >= 0 && ix < NXY && iy >= 0 && iy < NXY && iz == 0) {
        int b   = p / NP_PER_B;
        int bin = (b * NXY + ix) * NXY + iy;
        int seg = bin / 100;
        int iyl = bin % 100;
        int rep = blockIdx.x & (NREP - 1);       // round-robin ~ XCD-local
        int slot = atomicAdd(&segcnt[rep * NSEG + seg], 1);
        if (slot < CAPR) {
            segbuf[((((size_t)seg << 3) + rep) << CAPRSH) + slot] =
                ((unsigned int)p << 8) | (unsigned int)iyl;
        } else {                                  // astronomically rare; correct
            int o = atomicAdd(ovf_cnt, 1);
            if (o < OVF_CAP) { ovf[2 * o] = p; ovf[2 * o + 1] = bin; }
        }
    }
}

// ---- phase 2: stage + counting sort + double-buffered equal-split gather ----
__global__ __launch_bounds__(256, 4) void gather12(const float* __restrict__ x,
                                                   const int* __restrict__ segcnt,
                                                   const unsigned int* __restrict__ segbuf,
                                                   const int* __restrict__ ovf_cnt,
                                                   const int* __restrict__ ovf,
                                                   float* __restrict__ out) {
    __shared__ float        tile[100 * TSTRIDE];  // [iy_local][c]  26 KB
    __shared__ unsigned int raw[LSIZE];           // staged sub-lists  4 KB
    __shared__ unsigned int list[LSIZE];          // iy-sorted         4 KB
    __shared__ int          cnt[128];             // iy histogram
    __shared__ int          pfx[128];             // inclusive scan
    __shared__ int          cur128[128];          // scatter cursors
    __shared__ int          nsh[NREP];            // per-replica counts
    __shared__ int          bsh[NREP + 1];        // exclusive bases

    const int tid = threadIdx.x;
    const int seg = blockIdx.x;

    for (int f = tid; f < 100 * TSTRIDE; f += 256) tile[f] = 0.0f;
    if (tid < 128) { cnt[tid] = 0; }
    if (tid < NREP) nsh[tid] = min(segcnt[tid * NSEG + seg], CAPR);
    __syncthreads();
    if (tid == 0) {
        int s = 0;
        for (int r = 0; r < NREP; ++r) { bsh[r] = s; s += nsh[r]; }
        bsh[NREP] = s;
    }
    __syncthreads();

    // ---- stage 8 sub-lists -> raw[] (8 reps x 32 lanes, coalesced) ----
    {
        const int r  = tid >> 5;          // 0..7
        const int l3 = tid & 31;
        const unsigned int* src =
            segbuf + ((((size_t)seg << 3) + r) << CAPRSH);
        const int nr = nsh[r], br = bsh[r];
        for (int j = l3; j < nr; j += 32) raw[br + j] = src[j];
    }
    __syncthreads();

    const int n = bsh[NREP];              // <= 1024 by construction

    // ---- counting sort by iy_local ----
    for (int i = tid; i < n; i += 256) atomicAdd(&cnt[raw[i] & 0xFFu], 1);
    __syncthreads();
    if (tid < 128) pfx[tid] = cnt[tid];
    __syncthreads();
    for (int d = 1; d < 128; d <<= 1) {
        int t = 0;
        if (tid < 128 && tid >= d) t = pfx[tid - d];
        __syncthreads();
        if (tid < 128) pfx[tid] += t;
        __syncthreads();
    }
    if (tid < 128) cur128[tid] = pfx[tid] - cnt[tid];   // exclusive
    __syncthreads();
    for (int i = tid; i < n; i += 256) {
        const unsigned int pk = raw[i];
        const int pos = atomicAdd(&cur128[pk & 0xFFu], 1);
        list[pos] = pk;
    }
    __syncthreads();

    // ---- equal-split quarter-wave double-buffered gather ----
    const int wave = tid >> 6;
    const int lane = tid & 63;
    const int q    = lane >> 4;
    const int sl   = lane & 15;           // channels 4*sl..4*sl+3
    const int t16  = wave * 4 + q;        // block-quarter 0..15

    if (n > 0) {
        const float4* __restrict__ x4 = (const float4*)x;
        const int ps = (n * t16) >> 4;
        const int pe = (n * (t16 + 1)) >> 4;

        int   cur = -1;
        float ax = 0.f, ay = 0.f, az = 0.f, aw = 0.f;

#define LOAD_PK(PK, BASE)                                                   \
        _Pragma("unroll")                                                   \
        for (int u = 0; u < UNR; ++u) {                                     \
            int ii = (BASE) + u;                                            \
            ii = (ii < pe) ? ii : (pe - 1);                                 \
            ii = (ii < 0) ? 0 : ii;                                         \
            PK[u] = list[ii];                                               \
        }
#define ISSUE_V(V, PK)                                                      \
        _Pragma("unroll")                                                   \
        for (int u = 0; u < UNR; ++u)                                       \
            V[u] = x4[(size_t)(PK[u] >> 8) * 16 + sl];
#define ACC(PK, V, BASE)                                                    \
        _Pragma("unroll")                                                   \
        for (int u = 0; u < UNR; ++u) {                                     \
            const bool val = ((BASE) + u) < pe;                             \
            const int iyv  = val ? (int)(PK[u] & 0xFFu) : cur;              \
            const bool chg = (iyv != cur);                                  \
            if (chg && cur >= 0) {                                          \
                float* dst = &tile[cur * TSTRIDE + 4 * sl];                 \
                atomicAdd(dst + 0, ax); atomicAdd(dst + 1, ay);             \
                atomicAdd(dst + 2, az); atomicAdd(dst + 3, aw);             \
            }                                                               \
            const float mx = val ? V[u].x : 0.f;                            \
            const float my = val ? V[u].y : 0.f;                            \
            const float mz = val ? V[u].z : 0.f;                            \
            const float mw = val ? V[u].w : 0.f;                            \
            ax = chg ? V[u].x : ax + mx;                                    \
            ay = chg ? V[u].y : ay + my;                                    \
            az = chg ? V[u].z : az + mz;                                    \
            aw = chg ? V[u].w : aw + mw;                                    \
            cur = chg ? iyv : cur;                                          \
        }

        unsigned int pkA[UNR], pkB[UNR];
        float4 vA[UNR], vB[UNR];

        int i = ps;
        LOAD_PK(pkA, i);        ISSUE_V(vA, pkA);   // batch A in flight
        LOAD_PK(pkB, i + UNR);  ISSUE_V(vB, pkB);   // batch B in flight
        while (__any(i < pe)) {
            ACC(pkA, vA, i);                        // waits vA; vB stays out
            LOAD_PK(pkA, i + 2 * UNR);
            ISSUE_V(vA, pkA);                       // refill A
            ACC(pkB, vB, i + UNR);                  // waits vB; new A stays out
            LOAD_PK(pkB, i + 3 * UNR);
            ISSUE_V(vB, pkB);                       // refill B
            i += 2 * UNR;
        }
        if (cur >= 0) {                             // final flush
            float* dst = &tile[cur * TSTRIDE + 4 * sl];
            atomicAdd(dst + 0, ax); atomicAdd(dst + 1, ay);
            atomicAdd(dst + 2, az); atomicAdd(dst + 3, aw);
        }
#undef LOAD_PK
#undef ISSUE_V
#undef ACC
    }
    __syncthreads();

    // ---- fold overflow list (normally empty), wave 0 ----
    if (wave == 0) {
        const int bin0 = seg * 100;
        const int no = min(*ovf_cnt, OVF_CAP);
        for (int o = 0; o < no; ++o) {
            const int obin = ovf[2 * o + 1];
            if (obin >= bin0 && obin < bin0 + 100)
                tile[(obin - bin0) * TSTRIDE + lane] +=
                    x[(size_t)ovf[2 * o] * 64 + lane];
        }
    }
    __syncthreads();

    // ---- coalesced out-write ----
    const int b     = seg / 400;          // seg = b*400 + ix*2 + half
    const int ix    = (seg >> 1) % 200;
    const int hbase = (seg & 1) * 100;
    float* obase = out + (size_t)b * 64 * 40000 + (size_t)ix * 200 + hbase;
    for (int f = tid; f < 64 * 100; f += 256) {
        const int c  = f / 100;
        const int iy = f % 100;
        obase[(size_t)c * 40000 + iy] = tile[iy * TSTRIDE + c];
    }
}

// ---------------- fallback (round-1): direct atomic scatter ----------------
__global__ void lss_scatter_atomic(const float* __restrict__ x,
                                   const float* __restrict__ geom,
                                   float* __restrict__ out) {
    const int lane   = threadIdx.x & 63;
    const int wave   = (blockIdx.x * blockDim.x + threadIdx.x) >> 6;
    const int nwaves = (gridDim.x * blockDim.x) >> 6;
    for (int p = wave; p < NP; p += nwaves) {
        const float gx = geom[(size_t)p * 3 + 0];
        const float gy = geom[(size_t)p * 3 + 1];
        const float gz = geom[(size_t)p * 3 + 2];
        const int ix = (int)((gx + 50.0f) / 0.5f);
        const int iy = (int)((gy + 50.0f) / 0.5f);
        const int iz = (int)((gz + 10.0f) / 20.0f);
        if (ix >= 0 && ix < NXY && iy >= 0 && iy < NXY && iz == 0) {
            const int b = p / NP_PER_B;
            const float v = x[(size_t)p * 64 + lane];
            atomicAdd(&out[(((size_t)b * 64 + lane) * NXY + ix) * NXY + iy], v);
        }
    }
}

extern "C" void kernel_launch(void* const* d_in, const int* in_sizes, int n_in,
                              void* d_out, int out_size, void* d_ws, size_t ws_size,
                              hipStream_t stream) {
    const float* x    = (const float*)d_in[0];
    const float* geom = (const float*)d_in[1];
    float* out = (float*)d_out;

    // workspace carve-up
    char* ws = (char*)d_ws;
    size_t off = 0;
    int* segcnt  = (int*)(ws + off); off += (size_t)NREP * NSEG * 4;  // 100 KB
    int* ovf_cnt = (int*)(ws + off); off += 4;
    int* ovf     = (int*)(ws + off); off += (size_t)OVF_CAP * 2 * 4;
    unsigned int* segbuf = (unsigned int*)(ws + off);
    off += ((size_t)NSEG * NREP << CAPRSH) * 4;                       // 13.1 MB

    if (ws_size < off) {
        // fallback: direct atomic scatter
        hipMemsetAsync(out, 0, (size_t)out_size * sizeof(float), stream);
        lss_scatter_atomic<<<2048, 256, 0, stream>>>(x, geom, out);
        return;
    }

    // zero replica counters + overflow counter (contiguous, 100 KB)
    hipMemsetAsync(segcnt, 0, (size_t)NREP * NSEG * 4 + 4, stream);

    const int pblocks = (NP + 255) / 256;                 // 5412
    rep_scatter<<<pblocks, 256, 0, stream>>>(geom, segcnt, segbuf, ovf_cnt, ovf);
    gather12<<<NSEG, 256, 0, stream>>>(x, segcnt, segbuf, ovf_cnt, ovf, out);
}

// Round 16
// 166.319 us; speedup vs baseline: 1.3100x; 1.3100x over previous
//
#include <hip/hip_runtime.h>
#include <hip/hip_bf16.h>

// LSS voxel pooling, per-bin buckets (CAP=16, L2-resident) + double-buffered
// equal-split gather.  R14 structure, CAP 32->16.
//   x:    (B=8, N=6, D=41, H=16, W=44, C=64) f32
//   geom: (B, N, D, H, W, 3) f32
//   out:  (B, C=64, X=200, Y=200) f32
//
// bin = (b*200 + ix)*200 + iy,  kept iff 0<=ix<200, 0<=iy<200, iz==0
// (IEEE fp32 add + div + trunc-toward-zero matches reference .astype(int32))
//
// Pipeline (3 dispatches):
//   0 memset        : zero 320K bin counters + overflow counter (1.28 MB)
//   1 bucket_scatter: slot = atomicAdd(counts[bin]) -- 320K counters, chain
//                     depth ~3.4 (R11/R15: deeper chains = disaster);
//                     bucket[bin*16+slot] = (pid<<8)|iy%100. 20.5 MB buffer
//                     fits L2. Overflow (P~1.3e-7 per bin) -> global list
//                     folded by gather: correct regardless of cap.
//   2 gather11      : block = segment (100 bins = half (b,ix) row). Rebuild
//                     bin-grouped LDS list (128-wide scan, contiguous 6.4 KB
//                     bucket read, L2-hit). Equal 16-way point split across
//                     quarter-waves. Double-buffered x-load batches (2x6
//                     dwordx4 in flight -> vmcnt never drains). Interior
//                     iy-runs -> plain tile writes; head/tail partials ->
//                     32-slot scratch merged by wave 0. Coalesced out-write.

#define NP        1385472
#define NP_PER_B  173184      // N*D*H*W
#define NXY       200
#define NBIN      320000      // 8*200*200
#define NSEG      3200        // NBIN/100
#define CAP       16          // bucket capacity per bin (mean 3.4, P(>16)~1e-7)
#define CAPSH     4
#define OVF_CAP   4096
#define UNR       6           // x-loads per batch; 2 batches in flight
#define TSTRIDE   65          // tile row stride (odd -> conflict-free)
#define LSIZE     1024        // per-segment list cap (mean 341, >30 sigma)

// ---------------- phase 1: bucket points by bin (packed) ----------------
__global__ void bucket_scatter(const float* __restrict__ geom,
                               int* __restrict__ counts,
                               unsigned int* __restrict__ bucket,
                               int* __restrict__ ovf_cnt,
                               int* __restrict__ ovf) {
    int p = blockIdx.x * 256 + threadIdx.x;
    if (p >= NP) return;
    float gx = geom[(size_t)p * 3 + 0];
    float gy = geom[(size_t)p * 3 + 1];
    float gz = geom[(size_t)p * 3 + 2];
    int ix = (int)((gx + 50.0f) / 0.5f);
    int iy = (int)((gy + 50.0f) / 0.5f);
    int iz = (int)((gz + 10.0f) / 20.0f);
    if (ix >= 0 && ix < NXY && iy >= 0 && iy < NXY && iz == 0) {
        int b   = p / NP_PER_B;
        int bin = (b * NXY + ix) * NXY + iy;
        int slot = atomicAdd(&counts[bin], 1);
        if (slot < CAP) {
            bucket[((size_t)bin << CAPSH) + slot] =
                ((unsigned int)p << 8) | (unsigned int)(iy >= 100 ? iy - 100 : iy);
        } else {                       // ~1e-7/bin path; strict correctness
            int o = atomicAdd(ovf_cnt, 1);
            if (o < OVF_CAP) { ovf[2 * o] = p; ovf[2 * o + 1] = bin; }
        }
    }
}

// ---- phase 2: list rebuild + double-buffered equal-split gather ----
__global__ __launch_bounds__(256, 4) void gather11(const float* __restrict__ x,
                                                   const int* __restrict__ counts,
                                                   const unsigned int* __restrict__ bucket,
                                                   const int* __restrict__ ovf_cnt,
                                                   const int* __restrict__ ovf,
                                                   float* __restrict__ out) {
    __shared__ float        tile[100 * TSTRIDE];  // [iy_local][c]  26 KB
    __shared__ unsigned int list[LSIZE];          // bin-grouped (pid<<8|bl) 4 KB
    __shared__ float        scr[32][64];          // boundary partials  8 KB
    __shared__ int          scr_iy[32];
    __shared__ int          cnt[128];             // clamped per-bin counts
    __shared__ int          pfx[128];             // inclusive scan

    const int tid  = threadIdx.x;
    const int seg  = blockIdx.x;
    const int bin0 = seg * 100;

    for (int f = tid; f < 100 * TSTRIDE; f += 256) tile[f] = 0.0f;
    if (tid < 32) scr_iy[tid] = -1;
    if (tid < 128) {
        int c = (tid < 100) ? min(counts[bin0 + tid], CAP) : 0;
        cnt[tid] = c;
        pfx[tid] = c;
    }
    __syncthreads();
    for (int d = 1; d < 128; d <<= 1) {          // inclusive scan over 128
        int t = 0;
        if (tid < 128 && tid >= d) t = pfx[tid - d];
        __syncthreads();
        if (tid < 128) pfx[tid] += t;
        __syncthreads();
    }
    // rebuild bin-grouped list (bucket entries pre-packed); contiguous 6.4 KB
    for (int i = tid; i < 100 * CAP; i += 256) {
        const int bl = i >> CAPSH;
        const int s  = i & (CAP - 1);
        if (s < cnt[bl]) {
            const int pos = pfx[bl] - cnt[bl] + s;
            if (pos < LSIZE)
                list[pos] = bucket[((size_t)(bin0 + bl) << CAPSH) + s];
        }
    }
    __syncthreads();

    const int wave = tid >> 6;
    const int lane = tid & 63;
    const int q    = lane >> 4;          // quarter 0..3
    const int sl   = lane & 15;          // channels 4*sl..4*sl+3
    const int t16  = wave * 4 + q;       // block-quarter 0..15
    const int n    = min(pfx[99], LSIZE);

    if (n > 0) {
        const float4* __restrict__ x4 = (const float4*)x;
        const int ps = (n * t16) >> 4;
        const int pe = (n * (t16 + 1)) >> 4;

        int   cur   = -1;
        bool  first = true;
        float ax = 0.f, ay = 0.f, az = 0.f, aw = 0.f;

#define LOAD_PK(PK, BASE)                                                   \
        _Pragma("unroll")                                                   \
        for (int u = 0; u < UNR; ++u) {                                     \
            int ii = (BASE) + u;                                            \
            ii = (ii < pe) ? ii : (pe - 1);                                 \
            ii = (ii < 0) ? 0 : ii;                                         \
            PK[u] = list[ii];                                               \
        }
#define ISSUE_V(V, PK)                                                      \
        _Pragma("unroll")                                                   \
        for (int u = 0; u < UNR; ++u)                                       \
            V[u] = x4[(size_t)(PK[u] >> 8) * 16 + sl];
#define ACC(PK, V, BASE)                                                    \
        _Pragma("unroll")                                                   \
        for (int u = 0; u < UNR; ++u) {                                     \
            const bool val = ((BASE) + u) < pe;                             \
            const int iyv  = val ? (int)(PK[u] & 0xFFu) : cur;              \
            const bool chg = (iyv != cur);                                  \
            if (chg && cur >= 0) {                                          \
                if (first) {                                                \
                    float* dst = &scr[2 * t16][4 * sl];                     \
                    dst[0] = ax; dst[1] = ay; dst[2] = az; dst[3] = aw;     \
                    if (sl == 0) scr_iy[2 * t16] = cur;                     \
                    first = false;                                          \
                } else {                                                    \
                    float* dst = &tile[cur * TSTRIDE + 4 * sl];             \
                    dst[0] = ax; dst[1] = ay; dst[2] = az; dst[3] = aw;     \
                }                                                           \
            }                                                               \
            const float mx = val ? V[u].x : 0.f;                            \
            const float my = val ? V[u].y : 0.f;                            \
            const float mz = val ? V[u].z : 0.f;                            \
            const float mw = val ? V[u].w : 0.f;                            \
            ax = chg ? V[u].x : ax + mx;                                    \
            ay = chg ? V[u].y : ay + my;                                    \
            az = chg ? V[u].z : az + mz;                                    \
            aw = chg ? V[u].w : aw + mw;                                    \
            cur = chg ? iyv : cur;                                          \
        }

        unsigned int pkA[UNR], pkB[UNR];
        float4 vA[UNR], vB[UNR];

        int i = ps;
        LOAD_PK(pkA, i);        ISSUE_V(vA, pkA);     // batch A in flight
        LOAD_PK(pkB, i + UNR);  ISSUE_V(vB, pkB);     // batch B in flight
        while (__any(i < pe)) {
            ACC(pkA, vA, i);                          // waits vA only; vB stays out
            LOAD_PK(pkA, i + 2 * UNR);
            ISSUE_V(vA, pkA);                         // refill A (2 batches ahead)
            ACC(pkB, vB, i + UNR);                    // waits vB; new A stays out
            LOAD_PK(pkB, i + 3 * UNR);
            ISSUE_V(vB, pkB);                         // refill B
            i += 2 * UNR;
        }
        if (cur >= 0) {                   // tail run -> scratch (2t if also head)
            const int slot = first ? 2 * t16 : 2 * t16 + 1;
            float* dst = &scr[slot][4 * sl];
            dst[0] = ax; dst[1] = ay; dst[2] = az; dst[3] = aw;
            if (sl == 0) scr_iy[slot] = cur;
        }
#undef LOAD_PK
#undef ISSUE_V
#undef ACC
    }
    __syncthreads();

    // serial merge of <=32 boundary partials + overflow fold, by wave 0
    if (wave == 0) {
        for (int s = 0; s < 32; ++s) {
            const int iyv = scr_iy[s];
            if (iyv >= 0)
                tile[iyv * TSTRIDE + lane] += scr[s][lane];
        }
        const int no = min(*ovf_cnt, OVF_CAP);
        for (int o = 0; o < no; ++o) {   // normally zero iterations
            const int obin = ovf[2 * o + 1];
            if (obin >= bin0 && obin < bin0 + 100)
                tile[(obin - bin0) * TSTRIDE + lane] +=
                    x[(size_t)ovf[2 * o] * 64 + lane];
        }
    }
    __syncthreads();

    // ---- coalesced out-write ----
    const int b     = seg / 400;          // seg = b*400 + ix*2 + half
    const int ix    = (seg >> 1) % 200;
    const int hbase = (seg & 1) * 100;
    float* obase = out + (size_t)b * 64 * 40000 + (size_t)ix * 200 + hbase;
    for (int f = tid; f < 64 * 100; f += 256) {
        const int c  = f / 100;
        const int iy = f % 100;
        obase[(size_t)c * 40000 + iy] = tile[iy * TSTRIDE + c];
    }
}

// ---------------- fallback (round-1): direct atomic scatter ----------------
__global__ void lss_scatter_atomic(const float* __restrict__ x,
                                   const float* __restrict__ geom,
                                   float* __restrict__ out) {
    const int lane   = threadIdx.x & 63;
    const int wave   = (blockIdx.x * blockDim.x + threadIdx.x) >> 6;
    const int nwaves = (gridDim.x * blockDim.x) >> 6;
    for (int p = wave; p < NP; p += nwaves) {
        const float gx = geom[(size_t)p * 3 + 0];
        const float gy = geom[(size_t)p * 3 + 1];
        const float gz = geom[(size_t)p * 3 + 2];
        const int ix = (int)((gx + 50.0f) / 0.5f);
        const int iy = (int)((gy + 50.0f) / 0.5f);
        const int iz = (int)((gz + 10.0f) / 20.0f);
        if (ix >= 0 && ix < NXY && iy >= 0 && iy < NXY && iz == 0) {
            const int b = p / NP_PER_B;
            const float v = x[(size_t)p * 64 + lane];
            atomicAdd(&out[(((size_t)b * 64 + lane) * NXY + ix) * NXY + iy], v);
        }
    }
}

extern "C" void kernel_launch(void* const* d_in, const int* in_sizes, int n_in,
                              void* d_out, int out_size, void* d_ws, size_t ws_size,
                              hipStream_t stream) {
    const float* x    = (const float*)d_in[0];
    const float* geom = (const float*)d_in[1];
    float* out = (float*)d_out;

    // workspace carve-up
    char* ws = (char*)d_ws;
    size_t off = 0;
    int* counts  = (int*)(ws + off); off += (size_t)NBIN * 4;
    int* ovf_cnt = (int*)(ws + off); off += 4;
    int* ovf     = (int*)(ws + off); off += (size_t)OVF_CAP * 2 * 4;
    unsigned int* bucket = (unsigned int*)(ws + off);
    off += ((size_t)NBIN << CAPSH) * 4;      // 20.5 MB

    if (ws_size < off) {
        // fallback: direct atomic scatter
        hipMemsetAsync(out, 0, (size_t)out_size * sizeof(float), stream);
        lss_scatter_atomic<<<2048, 256, 0, stream>>>(x, geom, out);
        return;
    }

    // zero counts + overflow counter in one call (contiguous)
    hipMemsetAsync(counts, 0, (size_t)NBIN * 4 + 4, stream);

    const int pblocks = (NP + 255) / 256;                 // 5412
    bucket_scatter<<<pblocks, 256, 0, stream>>>(geom, counts, bucket, ovf_cnt, ovf);
    gather11<<<NSEG, 256, 0, stream>>>(x, counts, bucket, ovf_cnt, ovf, out);
}

// Round 17
// 165.119 us; speedup vs baseline: 1.3195x; 1.0073x over previous
//
#include <hip/hip_runtime.h>
#include <hip/hip_bf16.h>

// LSS voxel pooling, per-bin buckets (CAP=16, L2-resident) + bin-aligned
// double-buffered gather at 5 blocks/CU.
//   x:    (B=8, N=6, D=41, H=16, W=44, C=64) f32
//   geom: (B, N, D, H, W, 3) f32
//   out:  (B, C=64, X=200, Y=200) f32
//
// bin = (b*200 + ix)*200 + iy,  kept iff 0<=ix<200, 0<=iy<200, iz==0
// (IEEE fp32 add + div + trunc-toward-zero matches reference .astype(int32))
//
// Pipeline (3 dispatches):
//   0 memset        : zero 320K bin counters + overflow counter (1.28 MB)
//   1 bucket_scatter: slot = atomicAdd(counts[bin]) -- 320K counters, chain
//                     depth ~3.4 (R11/R15: deeper chains = disaster);
//                     bucket[bin*16+slot] = (pid<<8)|iy%100. 20.5 MB, L2-fit.
//                     Overflow -> global list folded by gather (correct
//                     regardless of cap).
//   2 gather13      : block = segment (100 bins = half (b,ix) row). Rebuild
//                     bin-grouped LDS list (128-wide scan, contiguous 6.4 KB
//                     bucket read, L2-hit). BIN-ALIGNED quarter ranges (R13:
//                     equal-split+scratch gained nothing; dropping scratch
//                     saves 8.2 KB -> 31 KB LDS -> 5 blocks/CU, 20 waves).
//                     Double-buffered float4 x loads (2x5 dwordx4 in flight),
//                     register run accumulation, plain tile writes (quarter-
//                     exclusive bins), coalesced out-write.

#define NP        1385472
#define NP_PER_B  173184      // N*D*H*W
#define NXY       200
#define NBIN      320000      // 8*200*200
#define NSEG      3200        // NBIN/100
#define CAP       16          // bucket capacity per bin (mean 3.4, P(>16)~1e-7)
#define CAPSH     4
#define OVF_CAP   4096
#define UNR       5           // x-loads per batch; 2 batches in flight (40 VGPR)
#define TSTRIDE   65          // tile row stride (odd -> conflict-free)
#define LSIZE     1024        // per-segment list cap (mean 341, >30 sigma)

// ---------------- phase 1: bucket points by bin (packed) ----------------
__global__ void bucket_scatter(const float* __restrict__ geom,
                               int* __restrict__ counts,
                               unsigned int* __restrict__ bucket,
                               int* __restrict__ ovf_cnt,
                               int* __restrict__ ovf) {
    int p = blockIdx.x * 256 + threadIdx.x;
    if (p >= NP) return;
    float gx = geom[(size_t)p * 3 + 0];
    float gy = geom[(size_t)p * 3 + 1];
    float gz = geom[(size_t)p * 3 + 2];
    int ix = (int)((gx + 50.0f) / 0.5f);
    int iy = (int)((gy + 50.0f) / 0.5f);
    int iz = (int)((gz + 10.0f) / 20.0f);
    if (ix >= 0 && ix < NXY && iy >= 0 && iy < NXY && iz == 0) {
        int b   = p / NP_PER_B;
        int bin = (b * NXY + ix) * NXY + iy;
        int slot = atomicAdd(&counts[bin], 1);
        if (slot < CAP) {
            bucket[((size_t)bin << CAPSH) + slot] =
                ((unsigned int)p << 8) | (unsigned int)(iy >= 100 ? iy - 100 : iy);
        } else {                       // ~1e-7/bin path; strict correctness
            int o = atomicAdd(ovf_cnt, 1);
            if (o < OVF_CAP) { ovf[2 * o] = p; ovf[2 * o + 1] = bin; }
        }
    }
}

// ---- phase 2: list rebuild + bin-aligned double-buffered gather ----
__global__ __launch_bounds__(256, 5) void gather13(const float* __restrict__ x,
                                                   const int* __restrict__ counts,
                                                   const unsigned int* __restrict__ bucket,
                                                   const int* __restrict__ ovf_cnt,
                                                   const int* __restrict__ ovf,
                                                   float* __restrict__ out) {
    __shared__ float        tile[100 * TSTRIDE];  // [iy_local][c]  26 KB
    __shared__ unsigned int list[LSIZE];          // bin-grouped (pid<<8|bl) 4 KB
    __shared__ int          cnt[128];             // clamped per-bin counts
    __shared__ int          pfx[128];             // inclusive scan

    const int tid  = threadIdx.x;
    const int seg  = blockIdx.x;
    const int bin0 = seg * 100;

    for (int f = tid; f < 100 * TSTRIDE; f += 256) tile[f] = 0.0f;
    if (tid < 128) {
        int c = (tid < 100) ? min(counts[bin0 + tid], CAP) : 0;
        cnt[tid] = c;
        pfx[tid] = c;
    }
    __syncthreads();
    for (int d = 1; d < 128; d <<= 1) {          // inclusive scan over 128
        int t = 0;
        if (tid < 128 && tid >= d) t = pfx[tid - d];
        __syncthreads();
        if (tid < 128) pfx[tid] += t;
        __syncthreads();
    }
    // rebuild bin-grouped list (bucket entries pre-packed); contiguous 6.4 KB
    for (int i = tid; i < 100 * CAP; i += 256) {
        const int bl = i >> CAPSH;
        const int s  = i & (CAP - 1);
        if (s < cnt[bl]) {
            const int pos = pfx[bl] - cnt[bl] + s;
            if (pos < LSIZE)
                list[pos] = bucket[((size_t)(bin0 + bl) << CAPSH) + s];
        }
    }
    __syncthreads();

    const int wave = tid >> 6;
    const int lane = tid & 63;
    const int q    = lane >> 4;          // quarter 0..3
    const int sl   = lane & 15;          // channels 4*sl..4*sl+3
    const int t16  = wave * 4 + q;       // block-quarter 0..15

    {
        const float4* __restrict__ x4 = (const float4*)x;
        // bin-aligned exclusive quarter ranges: quarters 0-3 own 7 bins,
        // quarters 4-15 own 6 bins (4*7 + 12*6 = 100)
        const int bs = (t16 < 4) ? t16 * 7 : 28 + (t16 - 4) * 6;
        const int be = bs + ((t16 < 4) ? 7 : 6);
        int ps = pfx[bs] - cnt[bs];
        int pe = (be < 100) ? (pfx[be] - cnt[be]) : pfx[99];
        ps = min(ps, LSIZE); pe = min(pe, LSIZE);

        int   cur = -1;
        float ax = 0.f, ay = 0.f, az = 0.f, aw = 0.f;

#define LOAD_PK(PK, BASE)                                                   \
        _Pragma("unroll")                                                   \
        for (int u = 0; u < UNR; ++u) {                                     \
            int ii = (BASE) + u;                                            \
            ii = (ii < pe) ? ii : (pe - 1);                                 \
            ii = (ii < 0) ? 0 : ii;                                         \
            PK[u] = list[ii];                                               \
        }
#define ISSUE_V(V, PK)                                                      \
        _Pragma("unroll")                                                   \
        for (int u = 0; u < UNR; ++u)                                       \
            V[u] = x4[(size_t)(PK[u] >> 8) * 16 + sl];
#define ACC(PK, V, BASE)                                                    \
        _Pragma("unroll")                                                   \
        for (int u = 0; u < UNR; ++u) {                                     \
            const bool val = ((BASE) + u) < pe;                             \
            const int iyv  = val ? (int)(PK[u] & 0xFFu) : cur;              \
            const bool chg = (iyv != cur);                                  \
            if (chg && cur >= 0) {    /* quarter-exclusive -> plain write */ \
                float* dst = &tile[cur * TSTRIDE + 4 * sl];                 \
                dst[0] = ax; dst[1] = ay; dst[2] = az; dst[3] = aw;         \
            }                                                               \
            const float mx = val ? V[u].x : 0.f;                            \
            const float my = val ? V[u].y : 0.f;                            \
            const float mz = val ? V[u].z : 0.f;                            \
            const float mw = val ? V[u].w : 0.f;                            \
            ax = chg ? V[u].x : ax + mx;                                    \
            ay = chg ? V[u].y : ay + my;                                    \
            az = chg ? V[u].z : az + mz;                                    \
            aw = chg ? V[u].w : aw + mw;                                    \
            cur = chg ? iyv : cur;                                          \
        }

        unsigned int pkA[UNR], pkB[UNR];
        float4 vA[UNR], vB[UNR];

        int i = ps;
        LOAD_PK(pkA, i);        ISSUE_V(vA, pkA);     // batch A in flight
        LOAD_PK(pkB, i + UNR);  ISSUE_V(vB, pkB);     // batch B in flight
        while (__any(i < pe)) {
            ACC(pkA, vA, i);                          // waits vA only; vB stays out
            LOAD_PK(pkA, i + 2 * UNR);
            ISSUE_V(vA, pkA);                         // refill A (2 batches ahead)
            ACC(pkB, vB, i + UNR);                    // waits vB; new A stays out
            LOAD_PK(pkB, i + 3 * UNR);
            ISSUE_V(vB, pkB);                         // refill B
            i += 2 * UNR;
        }
        if (cur >= 0) {                               // final flush
            float* dst = &tile[cur * TSTRIDE + 4 * sl];
            dst[0] = ax; dst[1] = ay; dst[2] = az; dst[3] = aw;
        }
#undef LOAD_PK
#undef ISSUE_V
#undef ACC
    }
    __syncthreads();

    // ---- fold overflow list (normally empty), wave 0 ----
    if (wave == 0) {
        const int no = min(*ovf_cnt, OVF_CAP);
        for (int o = 0; o < no; ++o) {   // normally zero iterations
            const int obin = ovf[2 * o + 1];
            if (obin >= bin0 && obin < bin0 + 100)
                tile[(obin - bin0) * TSTRIDE + lane] +=
                    x[(size_t)ovf[2 * o] * 64 + lane];
        }
    }
    __syncthreads();

    // ---- coalesced out-write ----
    const int b     = seg / 400;          // seg = b*400 + ix*2 + half
    const int ix    = (seg >> 1) % 200;
    const int hbase = (seg & 1) * 100;
    float* obase = out + (size_t)b * 64 * 40000 + (size_t)ix * 200 + hbase;
    for (int f = tid; f < 64 * 100; f += 256) {
        const int c  = f / 100;
        const int iy = f % 100;
        obase[(size_t)c * 40000 + iy] = tile[iy * TSTRIDE + c];
    }
}

// ---------------- fallback (round-1): direct atomic scatter ----------------
__global__ void lss_scatter_atomic(const float* __restrict__ x,
                                   const float* __restrict__ geom,
                                   float* __restrict__ out) {
    const int lane   = threadIdx.x & 63;
    const int wave   = (blockIdx.x * blockDim.x + threadIdx.x) >> 6;
    const int nwaves = (gridDim.x * blockDim.x) >> 6;
    for (int p = wave; p < NP; p += nwaves) {
        const float gx = geom[(size_t)p * 3 + 0];
        const float gy = geom[(size_t)p * 3 + 1];
        const float gz = geom[(size_t)p * 3 + 2];
        const int ix = (int)((gx + 50.0f) / 0.5f);
        const int iy = (int)((gy + 50.0f) / 0.5f);
        const int iz = (int)((gz + 10.0f) / 20.0f);
        if (ix >= 0 && ix < NXY && iy >= 0 && iy < NXY && iz == 0) {
            const int b = p / NP_PER_B;
            const float v = x[(size_t)p * 64 + lane];
            atomicAdd(&out[(((size_t)b * 64 + lane) * NXY + ix) * NXY + iy], v);
        }
    }
}

extern "C" void kernel_launch(void* const* d_in, const int* in_sizes, int n_in,
                              void* d_out, int out_size, void* d_ws, size_t ws_size,
                              hipStream_t stream) {
    const float* x    = (const float*)d_in[0];
    const float* geom = (const float*)d_in[1];
    float* out = (float*)d_out;

    // workspace carve-up
    char* ws = (char*)d_ws;
    size_t off = 0;
    int* counts  = (int*)(ws + off); off += (size_t)NBIN * 4;
    int* ovf_cnt = (int*)(ws + off); off += 4;
    int* ovf     = (int*)(ws + off); off += (size_t)OVF_CAP * 2 * 4;
    unsigned int* bucket = (unsigned int*)(ws + off);
    off += ((size_t)NBIN << CAPSH) * 4;      // 20.5 MB

    if (ws_size < off) {
        // fallback: direct atomic scatter
        hipMemsetAsync(out, 0, (size_t)out_size * sizeof(float), stream);
        lss_scatter_atomic<<<2048, 256, 0, stream>>>(x, geom, out);
        return;
    }

    // zero counts + overflow counter in one call (contiguous)
    hipMemsetAsync(counts, 0, (size_t)NBIN * 4 + 4, stream);

    const int pblocks = (NP + 255) / 256;                 // 5412
    bucket_scatter<<<pblocks, 256, 0, stream>>>(geom, counts, bucket, ovf_cnt, ovf);
    gather13<<<NSEG, 256, 0, stream>>>(x, counts, bucket, ovf_cnt, ovf, out);
}